// Round 14
// baseline (35.197 us; speedup 1.0000x reference)
//
#include <hip/hip_runtime.h>
#include <hip/hip_fp16.h>

#define BB 16384
#define LL 200
#define DD 100
#define VV 100000
#define CHUNK   50000          // f16 entries per LDS chunk: 100,000 B
#define CI4     6250           // int4 per chunk (50000*2/16)
#define PBLK    256            // pool blocks: 1/CU, all 256 CUs
#define PTHR    1024           // 16 waves/block
#define RPW     4              // rows per wave: 64 rows/block / 16 waves

// Kernel 1: rowdot[v] = sum_d E[v,d]*w[d], stored f16.
// Half-wave per row, lanes 0..24 load one float4. Both halves' results are
// packed into one __half2 store by lane 0 (r is even there).
// NOTE: the cross-lane __shfl MUST be executed by all lanes (uniform control
// flow) — R13 had it inside `if(lane==0)` which returned garbage (lane 32
// inactive under the exec mask). Hoisted out here.
__global__ __launch_bounds__(256) void rowdot_kernel(const float4* __restrict__ E4,
                                                     const float4* __restrict__ w4,
                                                     __half* __restrict__ rowdot) {
    const int tid  = blockIdx.x * blockDim.x + threadIdx.x;
    const int wave = tid >> 6;
    const int lane = threadIdx.x & 63;
    const int half = lane >> 5;
    const int sub  = lane & 31;

    float4 wv = make_float4(0.f, 0.f, 0.f, 0.f);
    if (sub < 25) wv = w4[sub];

    const int r = wave * 2 + half;
    float s = 0.0f;
    if (sub < 25) {
        float4 v = E4[(size_t)r * 25 + sub];
        s = v.x * wv.x + v.y * wv.y + v.z * wv.z + v.w * wv.w;
    }
    #pragma unroll
    for (int off = 16; off > 0; off >>= 1)
        s += __shfl_xor(s, off, 64);          // all 32 lanes of each half hold sum

    float s1 = __shfl(s, 32, 64);             // UNIFORM: every lane reads lane 32
    if (lane == 0) {
        __half2 h2;
        h2.x = __float2half(s);               // row r   (half 0 sum)
        h2.y = __float2half(s1);              // row r+1 (half 1 sum)
        *((__half2*)(rowdot + r)) = h2;       // r even -> 4B aligned
    }
}

// Kernel 2: LDS-staged f16 gather with REGISTER-PIPELINED staging.
// 256 blocks x 1024 threads, 64 rows/block (4/wave); lanes 0..49 hold each
// row's indices in regs. Chunk-0 loads + idx loads all issued back-to-back
// (11 int4 in flight); chunk-1 loads issued BEFORE probing chunk 0 so their
// latency hides under the probe phase.
__global__ __launch_bounds__(1024) void pool_kernel(const int4* __restrict__ idx4,
                                                    const __half* __restrict__ rowdot,
                                                    float* __restrict__ out) {
    __shared__ __half sh[CHUNK];
    const int t    = threadIdx.x;
    const int wave = t >> 6;                 // 0..15
    const int lane = t & 63;
    const int row0 = blockIdx.x * 64 + wave * RPW;
    const bool act = lane < 50;
    const int4* src = (const int4*)rowdot;   // 2*CI4 int4 total

    // ---- issue chunk-0 staging loads (7 int4, independent, in flight)
    int4 st[7];
    #pragma unroll
    for (int j = 0; j < 7; ++j) {
        int k = t + j * PTHR;
        if (k < CI4) st[j] = src[k];
    }
    // ---- issue idx loads (4 int4, also in flight)
    int4 pf[RPW];
    #pragma unroll
    for (int r = 0; r < RPW; ++r)
        pf[r] = act ? idx4[(size_t)(row0 + r) * 50 + lane]
                    : make_int4(0, 0, 0, 0);

    // ---- write chunk 0 to LDS
    #pragma unroll
    for (int j = 0; j < 7; ++j) {
        int k = t + j * PTHR;
        if (k < CI4) ((int4*)sh)[k] = st[j];
    }
    __syncthreads();

    // ---- issue chunk-1 staging loads (latency hides under probe of chunk 0)
    #pragma unroll
    for (int j = 0; j < 7; ++j) {
        int k = t + j * PTHR;
        if (k < CI4) st[j] = src[CI4 + k];
    }

    float acc[RPW] = {0.f, 0.f, 0.f, 0.f};
    // ---- probe chunk 0 (base 0)
    if (act) {
        #pragma unroll
        for (int r = 0; r < RPW; ++r) {
            int4 i4 = pf[r];
            if ((unsigned)i4.x < (unsigned)CHUNK) acc[r] += __half2float(sh[i4.x]);
            if ((unsigned)i4.y < (unsigned)CHUNK) acc[r] += __half2float(sh[i4.y]);
            if ((unsigned)i4.z < (unsigned)CHUNK) acc[r] += __half2float(sh[i4.z]);
            if ((unsigned)i4.w < (unsigned)CHUNK) acc[r] += __half2float(sh[i4.w]);
        }
    }
    __syncthreads();   // probes done before overwrite

    // ---- write chunk 1 to LDS
    #pragma unroll
    for (int j = 0; j < 7; ++j) {
        int k = t + j * PTHR;
        if (k < CI4) ((int4*)sh)[k] = st[j];
    }
    __syncthreads();

    // ---- probe chunk 1 (base CHUNK)
    if (act) {
        #pragma unroll
        for (int r = 0; r < RPW; ++r) {
            int4 i4 = pf[r];
            int a0 = i4.x - CHUNK, a1 = i4.y - CHUNK;
            int a2 = i4.z - CHUNK, a3 = i4.w - CHUNK;
            if ((unsigned)a0 < (unsigned)CHUNK) acc[r] += __half2float(sh[a0]);
            if ((unsigned)a1 < (unsigned)CHUNK) acc[r] += __half2float(sh[a1]);
            if ((unsigned)a2 < (unsigned)CHUNK) acc[r] += __half2float(sh[a2]);
            if ((unsigned)a3 < (unsigned)CHUNK) acc[r] += __half2float(sh[a3]);
        }
    }

    // ---- reduce across lanes and store
    #pragma unroll
    for (int r = 0; r < RPW; ++r) {
        float s = acc[r];
        #pragma unroll
        for (int off = 32; off > 0; off >>= 1)
            s += __shfl_xor(s, off, 64);
        if (lane == 0) out[row0 + r] = s * (1.0f / LL);
    }
}

extern "C" void kernel_launch(void* const* d_in, const int* in_sizes, int n_in,
                              void* d_out, int out_size, void* d_ws, size_t ws_size,
                              hipStream_t stream) {
    const int4*   idx4   = (const int4*)d_in[0];      // [B, L] int32 as int4
    const float4* E4     = (const float4*)d_in[1];    // [V, D] f32 as float4
    const float4* w4     = (const float4*)d_in[2];    // [D, 1] f32 as float4
    float*        out    = (float*)d_out;             // [B, 1] f32
    __half*       rowdot = (__half*)d_ws;             // 200 KB f16 table

    // 100000 rows, 2 rows/wave, 4 waves/block -> 12500 blocks
    rowdot_kernel<<<VV / 8, 256, 0, stream>>>(E4, w4, rowdot);
    // 16384 rows / 64 rows per block -> 256 blocks of 1024 threads
    pool_kernel<<<PBLK, PTHR, 0, stream>>>(idx4, rowdot, out);
}

// Round 15
// 24.608 us; speedup vs baseline: 1.4303x; 1.4303x over previous
//
#include <hip/hip_runtime.h>
#include <hip/hip_fp16.h>

#define BB 16384
#define LL 200
#define DD 100
#define VV 100000
#define CHUNK  50000           // f16 entries per LDS chunk: 100,000 B
#define NCHUNK 2               // 2 * 50000 = 100000 = VV exactly
#define PBLK   256             // pool blocks: 1/CU (100KB LDS), ALL 256 CUs
#define PTHR   1024            // 16 waves/block
#define RPW    4               // rows per wave: 64 rows/block / 16 waves

// Kernel 1: rowdot[v] = sum_d E[v,d]*w[d], stored f16.
// Half-wave per row, lanes 0..24 load one float4. Both halves' sums packed
// into one u32 (2 x f16) and stored NON-TEMPORALLY so the table bypasses the
// writing XCD's L2 (avoids cross-XCD dirty-line probes when pool stages it).
// Cross-lane __shfl executed by ALL lanes (R13 lesson: exec-masked shfl = garbage).
__global__ __launch_bounds__(256) void rowdot_kernel(const float4* __restrict__ E4,
                                                     const float4* __restrict__ w4,
                                                     __half* __restrict__ rowdot) {
    const int tid  = blockIdx.x * blockDim.x + threadIdx.x;
    const int wave = tid >> 6;
    const int lane = threadIdx.x & 63;
    const int half = lane >> 5;
    const int sub  = lane & 31;

    float4 wv = make_float4(0.f, 0.f, 0.f, 0.f);
    if (sub < 25) wv = w4[sub];

    const int r = wave * 2 + half;
    float s = 0.0f;
    if (sub < 25) {
        float4 v = E4[(size_t)r * 25 + sub];
        s = v.x * wv.x + v.y * wv.y + v.z * wv.z + v.w * wv.w;
    }
    #pragma unroll
    for (int off = 16; off > 0; off >>= 1)
        s += __shfl_xor(s, off, 64);          // all 32 lanes of each half hold sum

    float s1 = __shfl(s, 32, 64);             // UNIFORM: every lane reads lane 32
    if (lane == 0) {
        unsigned u0 = __half_as_ushort(__float2half(s));   // row r
        unsigned u1 = __half_as_ushort(__float2half(s1));  // row r+1
        unsigned packed = u0 | (u1 << 16);
        __builtin_nontemporal_store(packed, (unsigned*)rowdot + (r >> 1));
    }
}

// Kernel 2 (R12-proven): LDS-staged f16 gather. 256 blocks x 1024 threads,
// 64 rows/block (4 rows/wave); lanes 0..49 hold each row's indices in regs.
// 2 passes: stage 100KB chunk into LDS (simple unroll-1 coalesced loop —
// R14 showed hand-pipelining this REGRESSES; wave-level TLP covers it),
// barrier, predicated in-range accumulate from LDS, barrier.
__global__ __launch_bounds__(1024) void pool_kernel(const int4* __restrict__ idx4,
                                                    const __half* __restrict__ rowdot,
                                                    float* __restrict__ out) {
    __shared__ __half sh[CHUNK];
    const int t    = threadIdx.x;
    const int wave = t >> 6;                 // 0..15
    const int lane = t & 63;
    const int row0 = blockIdx.x * (PTHR / 64 * RPW) + wave * RPW;
    const bool act = lane < 50;

    // preload indices first (coalesced int4, overlaps the staging below)
    int4 pf[RPW];
    #pragma unroll
    for (int r = 0; r < RPW; ++r)
        pf[r] = act ? idx4[(size_t)(row0 + r) * 50 + lane]
                    : make_int4(0, 0, 0, 0);

    float acc[RPW];
    #pragma unroll
    for (int r = 0; r < RPW; ++r) acc[r] = 0.f;

    #pragma unroll 1
    for (int c = 0; c < NCHUNK; ++c) {
        const int base = c * CHUNK;
        __syncthreads();   // previous chunk's readers done before overwrite
        // stage CHUNK f16 = 6250 int4; 1024 threads -> 7 masked iters
        #pragma unroll 1
        for (int k = t; k < CHUNK * 2 / 16; k += PTHR)
            ((int4*)sh)[k] = ((const int4*)(rowdot))[base * 2 / 16 + k];
        __syncthreads();
        if (act) {
            #pragma unroll
            for (int r = 0; r < RPW; ++r) {
                int4 i4 = pf[r];
                int a0 = i4.x - base, a1 = i4.y - base;
                int a2 = i4.z - base, a3 = i4.w - base;
                if ((unsigned)a0 < (unsigned)CHUNK) acc[r] += __half2float(sh[a0]);
                if ((unsigned)a1 < (unsigned)CHUNK) acc[r] += __half2float(sh[a1]);
                if ((unsigned)a2 < (unsigned)CHUNK) acc[r] += __half2float(sh[a2]);
                if ((unsigned)a3 < (unsigned)CHUNK) acc[r] += __half2float(sh[a3]);
            }
        }
    }

    #pragma unroll
    for (int r = 0; r < RPW; ++r) {
        float s = acc[r];
        #pragma unroll
        for (int off = 32; off > 0; off >>= 1)
            s += __shfl_xor(s, off, 64);
        if (lane == 0) out[row0 + r] = s * (1.0f / LL);
    }
}

extern "C" void kernel_launch(void* const* d_in, const int* in_sizes, int n_in,
                              void* d_out, int out_size, void* d_ws, size_t ws_size,
                              hipStream_t stream) {
    const int4*   idx4   = (const int4*)d_in[0];      // [B, L] int32 as int4
    const float4* E4     = (const float4*)d_in[1];    // [V, D] f32 as float4
    const float4* w4     = (const float4*)d_in[2];    // [D, 1] f32 as float4
    float*        out    = (float*)d_out;             // [B, 1] f32
    __half*       rowdot = (__half*)d_ws;             // 200 KB f16 table

    // 100000 rows, 2 rows/wave, 4 waves/block -> 12500 blocks
    rowdot_kernel<<<VV / 8, 256, 0, stream>>>(E4, w4, rowdot);
    // 16384 rows / 64 rows per block -> 256 blocks of 1024 threads
    pool_kernel<<<PBLK, PTHR, 0, stream>>>(idx4, rowdot, out);
}

// Round 16
// 21.784 us; speedup vs baseline: 1.6157x; 1.1297x over previous
//
#include <hip/hip_runtime.h>
#include <hip/hip_fp16.h>

#define BB 16384
#define LL 200
#define DD 100
#define VV 100000
#define CHUNK  50000           // f16 entries per LDS chunk: 100,000 B
#define CI4    6250            // int4 per chunk (50000*2/16)
#define NCHUNK 2               // 2 * 50000 = 100000 = VV exactly
#define PBLK   256             // pool blocks: 1/CU (100KB LDS), ALL 256 CUs
#define PTHR   1024            // 16 waves/block
#define RPW    4               // rows per wave: 64 rows/block / 16 waves

// Kernel 1 (R12-exact, proven): rowdot[v] = sum_d E[v,d]*w[d], stored f16.
// Half-wave (32 lanes) per row, lanes 0..24 load one float4 (25 x 16B = row).
__global__ __launch_bounds__(256) void rowdot_kernel(const float4* __restrict__ E4,
                                                     const float4* __restrict__ w4,
                                                     __half* __restrict__ rowdot) {
    const int tid  = blockIdx.x * blockDim.x + threadIdx.x;
    const int wave = tid >> 6;
    const int lane = threadIdx.x & 63;
    const int half = lane >> 5;
    const int sub  = lane & 31;

    float4 wv = make_float4(0.f, 0.f, 0.f, 0.f);
    if (sub < 25) wv = w4[sub];

    const int r = wave * 2 + half;
    float s = 0.0f;
    if (sub < 25) {
        float4 v = E4[(size_t)r * 25 + sub];
        s = v.x * wv.x + v.y * wv.y + v.z * wv.z + v.w * wv.w;
    }
    #pragma unroll
    for (int off = 16; off > 0; off >>= 1)
        s += __shfl_xor(s, off, 64);
    if (sub == 0) rowdot[r] = __float2half(s);
}

// Kernel 2: LDS-staged f16 gather, staging via ASYNC global_load_lds (16B).
// 256 blocks x 1024 threads, 64 rows/block (4/wave); lanes 0..49 hold each
// row's indices in regs. Staging: each thread issues ~7 async DMA transfers
// back-to-back (no VGPR round-trip, no per-iteration vmcnt stall — R12's
// load->waitcnt->ds_write chain serialized at L2/L3 latency per iteration).
// LDS dest is wave-uniform base + lane*16 (linear layout) = the HW pattern.
__global__ __launch_bounds__(1024) void pool_kernel(const int4* __restrict__ idx4,
                                                    const __half* __restrict__ rowdot,
                                                    float* __restrict__ out) {
    __shared__ __half sh[CHUNK];
    const int t    = threadIdx.x;
    const int wv   = t >> 6;                 // wave id 0..15
    const int lane = t & 63;
    const int row0 = blockIdx.x * 64 + wv * RPW;
    const bool act = lane < 50;

    // preload indices first (coalesced int4, overlaps staging below)
    int4 pf[RPW];
    #pragma unroll
    for (int r = 0; r < RPW; ++r)
        pf[r] = act ? idx4[(size_t)(row0 + r) * 50 + lane]
                    : make_int4(0, 0, 0, 0);

    float acc[RPW] = {0.f, 0.f, 0.f, 0.f};
    const int4* src = (const int4*)rowdot;

    #pragma unroll 1
    for (int c = 0; c < NCHUNK; ++c) {
        const int base = c * CHUNK;
        __syncthreads();   // previous chunk's readers done before overwrite
        // async stage: int4 index k = j*1024 + t; LDS byte = k*16
        //  -> per (wave, j): uniform base = j*16384 + wv*1024, lane off = lane*16
        #pragma unroll
        for (int j = 0; j < 7; ++j) {
            const int k = j * PTHR + t;
            if (k < CI4) {
                const int4* gp = src + c * CI4 + k;                 // per-lane
                char* lb = (char*)sh + j * 16384 + wv * 1024;       // wave-uniform
                __builtin_amdgcn_global_load_lds(
                    (const __attribute__((address_space(1))) void*)gp,
                    (__attribute__((address_space(3))) void*)lb,
                    16, 0, 0);
            }
        }
        __syncthreads();   // drains vmcnt -> staged data visible in LDS
        if (act) {
            #pragma unroll
            for (int r = 0; r < RPW; ++r) {
                int4 i4 = pf[r];
                int a0 = i4.x - base, a1 = i4.y - base;
                int a2 = i4.z - base, a3 = i4.w - base;
                if ((unsigned)a0 < (unsigned)CHUNK) acc[r] += __half2float(sh[a0]);
                if ((unsigned)a1 < (unsigned)CHUNK) acc[r] += __half2float(sh[a1]);
                if ((unsigned)a2 < (unsigned)CHUNK) acc[r] += __half2float(sh[a2]);
                if ((unsigned)a3 < (unsigned)CHUNK) acc[r] += __half2float(sh[a3]);
            }
        }
    }

    #pragma unroll
    for (int r = 0; r < RPW; ++r) {
        float s = acc[r];
        #pragma unroll
        for (int off = 32; off > 0; off >>= 1)
            s += __shfl_xor(s, off, 64);
        if (lane == 0) out[row0 + r] = s * (1.0f / LL);
    }
}

extern "C" void kernel_launch(void* const* d_in, const int* in_sizes, int n_in,
                              void* d_out, int out_size, void* d_ws, size_t ws_size,
                              hipStream_t stream) {
    const int4*   idx4   = (const int4*)d_in[0];      // [B, L] int32 as int4
    const float4* E4     = (const float4*)d_in[1];    // [V, D] f32 as float4
    const float4* w4     = (const float4*)d_in[2];    // [D, 1] f32 as float4
    float*        out    = (float*)d_out;             // [B, 1] f32
    __half*       rowdot = (__half*)d_ws;             // 200 KB f16 table

    // 100000 rows, 2 rows/wave, 4 waves/block -> 12500 blocks
    rowdot_kernel<<<VV / 8, 256, 0, stream>>>(E4, w4, rowdot);
    // 16384 rows / 64 rows per block -> 256 blocks of 1024 threads
    pool_kernel<<<PBLK, PTHR, 0, stream>>>(idx4, rowdot, out);
}